// Round 8
// baseline (40.280 us; speedup 1.0000x reference)
//
#include <hip/hip_runtime.h>

// B=1048576, N=5, H=2, CLS=24, OUT=5.  h0=c0=0 -> w_hh dead, f-gate dead.
// Round-8: v6 + two scheduling fixes (theory: VALU-issue + latency-stall
// bound, occupancy possibly capped by >64 VGPR):
//  1. __launch_bounds__(256,8): pin VGPR <= 64 so 8 blocks/CU (20KB LDS)
//     is actually reachable (waves/SIMD halve at the 64-VGPR granule).
//  2. FC1/FC2 restructured: ALL B-fragment ds_reads batched before the
//     MFMAs, writes after -> one LDS latency per phase instead of four
//     serial read->mfma->write round-trips.

constexpr int Bc = 1048576;
constexpr int Nc = 5;

typedef __attribute__((ext_vector_type(8))) short bf16x8;
typedef __attribute__((ext_vector_type(4))) float f32x4;

__device__ __forceinline__ unsigned cvtpk(float lo, float hi) {
    unsigned r;
    asm("v_cvt_pk_bf16_f32 %0, %1, %2" : "=v"(r) : "v"(lo), "v"(hi));
    return r;
}
__device__ __forceinline__ float fast_sigmoid(float x) {
    return __builtin_amdgcn_rcpf(1.0f + __expf(-x));
}
// sigmoid(a)*tanh(b) with a single rcp: (e^{2b}-1) / ((e^{2b}+1)(1+e^{-a}))
__device__ __forceinline__ float sigtanh(float a, float b) {
    float ea = __expf(-a);
    float eb = __expf(2.0f * b);
    return (eb - 1.0f) * __builtin_amdgcn_rcpf((eb + 1.0f) * (1.0f + ea));
}
__device__ __forceinline__ bf16x8 as_bf16(uint4 v) {
    union { uint4 u; bf16x8 b; } c; c.u = v; return c.b;
}
__device__ __forceinline__ bf16x8 pack8(float4 a, float4 b) {
    uint4 h;
    h.x = cvtpk(a.x, a.y);
    h.y = cvtpk(a.z, a.w);
    h.z = cvtpk(b.x, b.y);
    h.w = cvtpk(b.z, b.w);
    return as_bf16(h);
}

__global__ __launch_bounds__(256, 8) void fused_rnn_mlp_v8(
    const float* __restrict__ seqs,    // [N,1,B,2]
    const float* __restrict__ others,  // [1,B,14]
    const float* __restrict__ w_ih,    // [N,8,2]
    const float* __restrict__ b_ih,    // [N,8]
    const float* __restrict__ b_hh,    // [N,8]
    const float* __restrict__ w1,      // [24,24]
    const float* __restrict__ b1,      // [24]
    const float* __restrict__ w2,      // [5,24]
    const float* __restrict__ b2,      // [5]
    float* __restrict__ out)           // [B,5]
{
    // per-wave region: 64 rows x 80 B = 5120 B.  Sigma scratch (64 x 32 B)
    // aliases bytes [0,2048): FC2 batched reads complete BEFORE any scratch
    // write; all traffic is wave-private and the DS pipe is in-order.
    __shared__ unsigned char lds_all[4 * 5120];
    const int tid  = threadIdx.x;
    const int lane = tid & 63;
    const int wid  = tid >> 6;
    const int qt   = lane >> 4;
    const int rlo  = lane & 15;
    unsigned char* wb = lds_all + wid * 5120;

    const int elem = blockIdx.x * 256 + tid;

    // ---------- issue ALL global loads up front (latency overlap) ----------
    float2 x[Nc];
#pragma unroll
    for (int n = 0; n < Nc; n++)
        x[n] = *reinterpret_cast<const float2*>(seqs + ((size_t)n * Bc + elem) * 2);
    float2 oth[7];
    {
        const float2* op = reinterpret_cast<const float2*>(others + (size_t)elem * 14);
#pragma unroll
        for (int j = 0; j < 7; j++) oth[j] = op[j];
    }
    // weight rows for A-fragments (per-lane VMEM, L1-hot)
    const int k0 = 8 * qt;
    float4 w1r[2][2], w2r[2];
#pragma unroll
    for (int mt = 0; mt < 2; mt++) {
        const int j = rlo + 16 * mt;
        const bool v = (j < 24) && (k0 < 24);
        const float* p = w1 + j * 24 + k0;
        w1r[mt][0] = v ? *reinterpret_cast<const float4*>(p)
                       : make_float4(0.f, 0.f, 0.f, 0.f);
        w1r[mt][1] = v ? *reinterpret_cast<const float4*>(p + 4)
                       : make_float4(0.f, 0.f, 0.f, 0.f);
    }
    {
        const bool v = (rlo < 5) && (k0 < 24);
        const float* p = w2 + rlo * 24 + k0;
        w2r[0] = v ? *reinterpret_cast<const float4*>(p)
                   : make_float4(0.f, 0.f, 0.f, 0.f);
        w2r[1] = v ? *reinterpret_cast<const float4*>(p + 4)
                   : make_float4(0.f, 0.f, 0.f, 0.f);
    }
    float4 b1v[2], b2v;
#pragma unroll
    for (int mt = 0; mt < 2; mt++)
        b1v[mt] = (16*mt + 4*qt < 24)
                    ? *reinterpret_cast<const float4*>(b1 + 16*mt + 4*qt)
                    : make_float4(0.f, 0.f, 0.f, 0.f);
    b2v = (qt == 0) ? *reinterpret_cast<const float4*>(b2)
                    : make_float4(b2[4], 0.f, 0.f, 0.f);

    // ---------- LSTM (one step, h0=c0=0), biases via uniform s_loads ----------
    float f[24];
#pragma unroll
    for (int n = 0; n < Nc; n++) {
        const float* w = w_ih + n * 16;   // gate rows i(0,1) f(2,3) g(4,5) o(6,7)
        const float bi0 = b_ih[n*8+0] + b_hh[n*8+0];
        const float bi1 = b_ih[n*8+1] + b_hh[n*8+1];
        const float bg0 = b_ih[n*8+4] + b_hh[n*8+4];
        const float bg1 = b_ih[n*8+5] + b_hh[n*8+5];
        const float bo0 = b_ih[n*8+6] + b_hh[n*8+6];
        const float bo1 = b_ih[n*8+7] + b_hh[n*8+7];
        float gi0 = fmaf(x[n].x, w[0],  fmaf(x[n].y, w[1],  bi0));
        float gi1 = fmaf(x[n].x, w[2],  fmaf(x[n].y, w[3],  bi1));
        float gg0 = fmaf(x[n].x, w[8],  fmaf(x[n].y, w[9],  bg0));
        float gg1 = fmaf(x[n].x, w[10], fmaf(x[n].y, w[11], bg1));
        float go0 = fmaf(x[n].x, w[12], fmaf(x[n].y, w[13], bo0));
        float go1 = fmaf(x[n].x, w[14], fmaf(x[n].y, w[15], bo1));
        float c0 = sigtanh(gi0, gg0);       // sigmoid(i)*tanh(g)
        float c1 = sigtanh(gi1, gg1);
        f[n*2+0] = sigtanh(go0, c0);        // sigmoid(o)*tanh(c)
        f[n*2+1] = sigtanh(go1, c1);
    }
#pragma unroll
    for (int j = 0; j < 7; j++) {
        f[10 + 2*j]     = oth[j].x;
        f[10 + 2*j + 1] = oth[j].y;
    }

    // ---------- feats -> LDS bf16 (row=lane, bytes 0..47 data, 48..63 zero) ----------
    {
        unsigned d[12];
#pragma unroll
        for (int p = 0; p < 12; p++) d[p] = cvtpk(f[2*p], f[2*p+1]);
        unsigned char* rp = wb + lane * 80;
        *reinterpret_cast<uint4*>(rp     ) = make_uint4(d[0], d[1], d[2],  d[3]);
        *reinterpret_cast<uint4*>(rp + 16) = make_uint4(d[4], d[5], d[6],  d[7]);
        *reinterpret_cast<uint4*>(rp + 32) = make_uint4(d[8], d[9], d[10], d[11]);
        *reinterpret_cast<uint4*>(rp + 48) = make_uint4(0u, 0u, 0u, 0u);
    }

    // ---------- A fragments (pack overlaps the LDS writes draining) ----------
    bf16x8 A1[2], A2;
#pragma unroll
    for (int mt = 0; mt < 2; mt++) A1[mt] = pack8(w1r[mt][0], w1r[mt][1]);
    A2 = pack8(w2r[0], w2r[1]);

    // ---------- FC1: batched reads -> MFMAs -> batched writes ----------
    // C layout [HW-verified r4]: col = lane&15 (batch row), row = 4*qt + reg.
    bf16x8 Bv[4];
#pragma unroll
    for (int nt = 0; nt < 4; nt++)
        Bv[nt] = as_bf16(*reinterpret_cast<const uint4*>(
            wb + (16*nt + rlo) * 80 + qt * 16));
#pragma unroll
    for (int nt = 0; nt < 4; nt++) {
#pragma unroll
        for (int mt = 0; mt < 2; mt++) {
            f32x4 a = { b1v[mt].x, b1v[mt].y, b1v[mt].z, b1v[mt].w };
            a = __builtin_amdgcn_mfma_f32_16x16x32_bf16(A1[mt], Bv[nt], a, 0, 0, 0);
            const unsigned p0 = cvtpk(fmaxf(a[0], 0.0f), fmaxf(a[1], 0.0f));
            const unsigned p1 = cvtpk(fmaxf(a[2], 0.0f), fmaxf(a[3], 0.0f));
            // hidden[batch][j=16mt+4qt+0..3] at bytes 2j; j>=24 writes zeros
            *reinterpret_cast<uint2*>(wb + (16*nt + rlo) * 80 + (32*mt + 8*qt)) =
                make_uint2(p0, p1);
        }
    }

    // ---------- FC2: batched reads -> MFMAs -> scratch transpose ----------
#pragma unroll
    for (int nt = 0; nt < 4; nt++)
        Bv[nt] = as_bf16(*reinterpret_cast<const uint4*>(
            wb + (16*nt + rlo) * 80 + qt * 16));
#pragma unroll
    for (int nt = 0; nt < 4; nt++) {
        f32x4 a = { b2v.x, b2v.y, b2v.z, b2v.w };
        a = __builtin_amdgcn_mfma_f32_16x16x32_bf16(A2, Bv[nt], a, 0, 0, 0);
        if (qt == 0) {          // rows q=0..3
            *reinterpret_cast<float4*>(wb + (16*nt + rlo) * 32) =
                make_float4(a[0], a[1], a[2], a[3]);
        } else if (qt == 1) {   // row q=4 (reg 0)
            *reinterpret_cast<float*>(wb + (16*nt + rlo) * 32 + 16) = a[0];
        }
    }
    // each lane sigmoids + stores its OWN element's 5 outputs
    {
        const float4 v  = *reinterpret_cast<const float4*>(wb + lane * 32);
        const float  v4 = *reinterpret_cast<const float*>(wb + lane * 32 + 16);
        float* o = out + (size_t)elem * 5;
        o[0] = fast_sigmoid(v.x);
        o[1] = fast_sigmoid(v.y);
        o[2] = fast_sigmoid(v.z);
        o[3] = fast_sigmoid(v.w);
        o[4] = fast_sigmoid(v4);
    }
}

extern "C" void kernel_launch(void* const* d_in, const int* in_sizes, int n_in,
                              void* d_out, int out_size, void* d_ws, size_t ws_size,
                              hipStream_t stream) {
    const float* seqs   = (const float*)d_in[0];
    const float* others = (const float*)d_in[1];
    const float* w_ih   = (const float*)d_in[2];
    // d_in[3] = w_hh : dead (h0 = 0)
    const float* b_ih   = (const float*)d_in[4];
    const float* b_hh   = (const float*)d_in[5];
    const float* w1     = (const float*)d_in[6];
    const float* b1     = (const float*)d_in[7];
    const float* w2     = (const float*)d_in[8];
    const float* b2     = (const float*)d_in[9];
    float* out = (float*)d_out;

    dim3 grid(Bc / 256), block(256);
    fused_rnn_mlp_v8<<<grid, block, 0, stream>>>(
        seqs, others, w_ih, b_ih, b_hh, w1, b1, w2, b2, out);
}

// Round 9
// 32.560 us; speedup vs baseline: 1.2371x; 1.2371x over previous
//
#include <hip/hip_runtime.h>

// B=1048576, N=5, H=2, CLS=24, OUT=5.  h0=c0=0 -> w_hh dead, f-gate dead.
// Round-9: ZERO-LDS design. Round-8 spills proved occupancy wasn't the
// limiter; v6's cost was the LDS round-trips (2x ~120cy DS latency, ~27 DS
// ops, 1.67M bank conflicts). FC1/FC2 now use mfma_f32_32x32x16_bf16 whose
// 32-col C layout lets ALL fragment shuffles be done with __shfl_xor(.,32)
// (lane<->lane+32) + cndmask: no LDS, no barriers, no bank conflicts.
//   FC1: hidden^T = relu(w1 @ feats^T + b1)   (M=feature j, N=batch, K=24+pad)
//   FC2: out^T    = sigm(w2 @ hidden^T + b2)  (M=q, N=batch, K=24+pad)
// Per wave: 2 column-tiles of 32 elems; 8 MFMAs total. Numeric path identical
// to v6 (same bf16 roundings) -> absmax expected unchanged.

constexpr int Bc = 1048576;
constexpr int Nc = 5;

typedef __attribute__((ext_vector_type(8))) short bf16x8;
typedef __attribute__((ext_vector_type(16))) float f32x16;

__device__ __forceinline__ unsigned cvtpk(float lo, float hi) {
    unsigned r;
    asm("v_cvt_pk_bf16_f32 %0, %1, %2" : "=v"(r) : "v"(lo), "v"(hi));
    return r;
}
__device__ __forceinline__ float fast_sigmoid(float x) {
    return __builtin_amdgcn_rcpf(1.0f + __expf(-x));
}
// sigmoid(a)*tanh(b) with a single rcp
__device__ __forceinline__ float sigtanh(float a, float b) {
    float ea = __expf(-a);
    float eb = __expf(2.0f * b);
    return (eb - 1.0f) * __builtin_amdgcn_rcpf((eb + 1.0f) * (1.0f + ea));
}
__device__ __forceinline__ bf16x8 mk_frag(unsigned a, unsigned b,
                                          unsigned c, unsigned d) {
    union { uint4 u; bf16x8 v; } x;
    x.u = make_uint4(a, b, c, d);
    return x.v;
}
// 8 consecutive floats of one weight row -> bf16 fragment (zeros if !valid;
// conditional load keeps OOB rows from reading past the buffer)
__device__ __forceinline__ bf16x8 pack_row8(const float* row, bool valid) {
    unsigned h0 = 0, h1 = 0, h2 = 0, h3 = 0;
    if (valid) {
        float4 a = *reinterpret_cast<const float4*>(row);
        float4 b = *reinterpret_cast<const float4*>(row + 4);
        h0 = cvtpk(a.x, a.y); h1 = cvtpk(a.z, a.w);
        h2 = cvtpk(b.x, b.y); h3 = cvtpk(b.z, b.w);
    }
    return mk_frag(h0, h1, h2, h3);
}

__global__ __launch_bounds__(256) void fused_rnn_mlp_v9(
    const float* __restrict__ seqs,    // [N,1,B,2]
    const float* __restrict__ others,  // [1,B,14]
    const float* __restrict__ w_ih,    // [N,8,2]
    const float* __restrict__ b_ih,    // [N,8]
    const float* __restrict__ b_hh,    // [N,8]
    const float* __restrict__ w1,      // [24,24]
    const float* __restrict__ b1,      // [24]
    const float* __restrict__ w2,      // [5,24]
    const float* __restrict__ b2,      // [5]
    float* __restrict__ out)           // [B,5]
{
    const int tid  = threadIdx.x;
    const int lane = tid & 63;
    const int lo31 = lane & 31;        // elem-in-tile / weight row
    const int kh   = lane >> 5;        // 0: lanes 0-31, 1: lanes 32-63
    const int elem = blockIdx.x * 256 + tid;
    const int wbase = blockIdx.x * 256 + (tid >> 6) * 64;   // wave's elem base

    // ---------- global loads ----------
    float2 x[Nc];
#pragma unroll
    for (int n = 0; n < Nc; n++)
        x[n] = *reinterpret_cast<const float2*>(seqs + ((size_t)n * Bc + elem) * 2);
    float2 oth[7];
    {
        const float2* op = reinterpret_cast<const float2*>(others + (size_t)elem * 14);
#pragma unroll
        for (int j = 0; j < 7; j++) oth[j] = op[j];
    }

    // ---------- LSTM (one step, h0=c0=0); pack feats straight into d[12] ----------
    unsigned d[12];
#pragma unroll
    for (int n = 0; n < Nc; n++) {
        const float* w = w_ih + n * 16;   // gate rows i(0,1) f(2,3) g(4,5) o(6,7)
        const float bi0 = b_ih[n*8+0] + b_hh[n*8+0];
        const float bi1 = b_ih[n*8+1] + b_hh[n*8+1];
        const float bg0 = b_ih[n*8+4] + b_hh[n*8+4];
        const float bg1 = b_ih[n*8+5] + b_hh[n*8+5];
        const float bo0 = b_ih[n*8+6] + b_hh[n*8+6];
        const float bo1 = b_ih[n*8+7] + b_hh[n*8+7];
        float gi0 = fmaf(x[n].x, w[0],  fmaf(x[n].y, w[1],  bi0));
        float gi1 = fmaf(x[n].x, w[2],  fmaf(x[n].y, w[3],  bi1));
        float gg0 = fmaf(x[n].x, w[8],  fmaf(x[n].y, w[9],  bg0));
        float gg1 = fmaf(x[n].x, w[10], fmaf(x[n].y, w[11], bg1));
        float go0 = fmaf(x[n].x, w[12], fmaf(x[n].y, w[13], bo0));
        float go1 = fmaf(x[n].x, w[14], fmaf(x[n].y, w[15], bo1));
        float c0 = sigtanh(gi0, gg0);
        float c1 = sigtanh(gi1, gg1);
        d[n] = cvtpk(sigtanh(go0, c0), sigtanh(go1, c1));   // features 2n,2n+1
    }
#pragma unroll
    for (int j = 0; j < 7; j++)
        d[5 + j] = cvtpk(oth[j].x, oth[j].y);               // features 10..23

    // ---------- cross-half copies of feats (lane <-> lane^32) ----------
    unsigned sd[12];
#pragma unroll
    for (int i = 0; i < 12; i++) sd[i] = __shfl_xor(d[i], 32);

    // B-fragments for FC1 (K-major pairs; dword m = features (8kh+2m, 8kh+2m+1)):
    //  tile0 (cols = elems of lanes 0-31): k0-15: lo=own d0-3, hi=partner d4-7
    //  tile1 (cols = elems of lanes 32-63): k0-15: lo=partner d0-3, hi=own d4-7
    //  k16-31: lo = d8-11 (own / partner), hi = zero-pad
    unsigned b0a[4], b1a[4], b0b[4], b1b[4];
#pragma unroll
    for (int i = 0; i < 4; i++) {
        b0a[i] = kh ? sd[4+i] : d[i];
        b1a[i] = kh ? d[4+i]  : sd[i];
        b0b[i] = kh ? 0u      : d[8+i];
        b1b[i] = kh ? 0u      : sd[8+i];
    }

    // ---------- A-fragments (weights; row = lo31, k = 8kh+i), zero-padded ----------
    bf16x8 A1a = pack_row8(w1 + lo31 * 24 + 8 * kh, lo31 < 24);
    bf16x8 A1b = pack_row8(w1 + lo31 * 24 + 16, (lo31 < 24) && (kh == 0));
    bf16x8 A2a = pack_row8(w2 + lo31 * 24 + 8 * kh, lo31 < 5);
    bf16x8 A2b = pack_row8(w2 + lo31 * 24 + 16, (lo31 < 5) && (kh == 0));

    // ---------- C1 init = b1[row(reg,lane)] (rows >=24 are the zero pad) ----------
    f32x16 c1z;
#pragma unroll
    for (int r = 0; r < 16; r++) {
        const int jb = (r & 3) + 8 * (r >> 2);        // row for kh=0
        float v = 0.0f;
        if (jb < 24) v = kh ? b1[jb + 4] : b1[jb];    // jb+4 <= 23 when jb<24 here
        if (jb >= 24) v = 0.0f;
        c1z[r] = v;
    }
    f32x16 accA = c1z, accB = c1z;

    // ---------- FC1: 4 MFMAs (2 K-chunks x 2 tiles) ----------
    accA = __builtin_amdgcn_mfma_f32_32x32x16_bf16(
        A1a, mk_frag(b0a[0], b0a[1], b0a[2], b0a[3]), accA, 0, 0, 0);
    accA = __builtin_amdgcn_mfma_f32_32x32x16_bf16(
        A1b, mk_frag(b0b[0], b0b[1], b0b[2], b0b[3]), accA, 0, 0, 0);
    accB = __builtin_amdgcn_mfma_f32_32x32x16_bf16(
        A1a, mk_frag(b1a[0], b1a[1], b1a[2], b1a[3]), accB, 0, 0, 0);
    accB = __builtin_amdgcn_mfma_f32_32x32x16_bf16(
        A1b, mk_frag(b1b[0], b1b[1], b1b[2], b1b[3]), accB, 0, 0, 0);

    // ---------- FC2 + sigmoid + store, per tile ----------
#pragma unroll
    for (int t = 0; t < 2; t++) {
        const f32x16 acc = t ? accB : accA;
        // relu + pack hidden rows held by this lane (regs 0-11 = rows j<24)
        unsigned p0 = cvtpk(fmaxf(acc[0],  0.f), fmaxf(acc[1],  0.f));
        unsigned p1 = cvtpk(fmaxf(acc[2],  0.f), fmaxf(acc[3],  0.f));
        unsigned p2 = cvtpk(fmaxf(acc[4],  0.f), fmaxf(acc[5],  0.f));
        unsigned p3 = cvtpk(fmaxf(acc[6],  0.f), fmaxf(acc[7],  0.f));
        unsigned p4 = cvtpk(fmaxf(acc[8],  0.f), fmaxf(acc[9],  0.f));
        unsigned p5 = cvtpk(fmaxf(acc[10], 0.f), fmaxf(acc[11], 0.f));
        const unsigned q0 = __shfl_xor(p0, 32);
        const unsigned q1 = __shfl_xor(p1, 32);
        const unsigned q2 = __shfl_xor(p2, 32);
        const unsigned q3 = __shfl_xor(p3, 32);
        const unsigned q4 = __shfl_xor(p4, 32);
        const unsigned q5 = __shfl_xor(p5, 32);
        // B2 k0-15:  lo: [p0 p1 q0 q1] (j0-7)   hi: [q2 q3 p2 p3] (j8-15)
        // B2 k16-31: lo: [p4 p5 q4 q5] (j16-23) hi: zero (j24-31 pad)
        const bf16x8 B2a = mk_frag(kh ? q2 : p0, kh ? q3 : p1,
                                   kh ? p2 : q0, kh ? p3 : q1);
        const bf16x8 B2b = mk_frag(kh ? 0u : p4, kh ? 0u : p5,
                                   kh ? 0u : q4, kh ? 0u : q5);
        // C2 init = b2[q]; lane-lo rows 0-3 = q0-3, lane-hi reg0 = q4
        f32x16 c2;
#pragma unroll
        for (int r = 0; r < 16; r++) c2[r] = 0.0f;
        c2[0] = kh ? b2[4] : b2[0];
        if (!kh) { c2[1] = b2[1]; c2[2] = b2[2]; c2[3] = b2[3]; }
        c2 = __builtin_amdgcn_mfma_f32_32x32x16_bf16(A2a, B2a, c2, 0, 0, 0);
        c2 = __builtin_amdgcn_mfma_f32_32x32x16_bf16(A2b, B2b, c2, 0, 0, 0);

        const float s0 = fast_sigmoid(c2[0]);
        const float s1 = fast_sigmoid(c2[1]);
        const float s2 = fast_sigmoid(c2[2]);
        const float s3 = fast_sigmoid(c2[3]);
        const int et = wbase + t * 32 + lo31;   // this column's batch element
        float* o = out + (size_t)et * 5;
        if (kh == 0) {          // rows q=0..3
            o[0] = s0; o[1] = s1; o[2] = s2; o[3] = s3;
        } else {                // row q=4 (reg 0)
            o[4] = s0;
        }
    }
}

extern "C" void kernel_launch(void* const* d_in, const int* in_sizes, int n_in,
                              void* d_out, int out_size, void* d_ws, size_t ws_size,
                              hipStream_t stream) {
    const float* seqs   = (const float*)d_in[0];
    const float* others = (const float*)d_in[1];
    const float* w_ih   = (const float*)d_in[2];
    // d_in[3] = w_hh : dead (h0 = 0)
    const float* b_ih   = (const float*)d_in[4];
    const float* b_hh   = (const float*)d_in[5];
    const float* w1     = (const float*)d_in[6];
    const float* b1     = (const float*)d_in[7];
    const float* w2     = (const float*)d_in[8];
    const float* b2     = (const float*)d_in[9];
    float* out = (float*)d_out;

    dim3 grid(Bc / 256), block(256);
    fused_rnn_mlp_v9<<<grid, block, 0, stream>>>(
        seqs, others, w_ih, b_ih, b_hh, w1, b1, w2, b2, out);
}

// Round 10
// 30.737 us; speedup vs baseline: 1.3105x; 1.0593x over previous
//
#include <hip/hip_runtime.h>

// B=1048576, N=5, H=2, CLS=24, OUT=5.  h0=c0=0 -> w_hh dead, f-gate dead.
// Round-10: v9 (zero-LDS, 32x32x16 MFMA, shfl_xor(32) fragment exchange —
// layout HW-validated in r9) + 2 independent element-groups per wave.
// r9 counters (VALUBusy 44 / Mfma 3.6 / HBM 21 / Occ 41, VGPR only 44) say
// LATENCY-bound: one serial chain per thread. Two independent groups give
// the scheduler cross-group ILP and amortize ~130 cyc/wave of fixed cost
// (weight-fragment packing, c1z build, bias s_loads).

constexpr int Bc = 1048576;
constexpr int Nc = 5;

typedef __attribute__((ext_vector_type(8))) short bf16x8;
typedef __attribute__((ext_vector_type(16))) float f32x16;

__device__ __forceinline__ unsigned cvtpk(float lo, float hi) {
    unsigned r;
    asm("v_cvt_pk_bf16_f32 %0, %1, %2" : "=v"(r) : "v"(lo), "v"(hi));
    return r;
}
__device__ __forceinline__ float fast_sigmoid(float x) {
    return __builtin_amdgcn_rcpf(1.0f + __expf(-x));
}
// sigmoid(a)*tanh(b) with a single rcp
__device__ __forceinline__ float sigtanh(float a, float b) {
    float ea = __expf(-a);
    float eb = __expf(2.0f * b);
    return (eb - 1.0f) * __builtin_amdgcn_rcpf((eb + 1.0f) * (1.0f + ea));
}
__device__ __forceinline__ bf16x8 mk_frag(unsigned a, unsigned b,
                                          unsigned c, unsigned d) {
    union { uint4 u; bf16x8 v; } x;
    x.u = make_uint4(a, b, c, d);
    return x.v;
}
// 8 consecutive floats of one weight row -> bf16 fragment (zeros if !valid)
__device__ __forceinline__ bf16x8 pack_row8(const float* row, bool valid) {
    unsigned h0 = 0, h1 = 0, h2 = 0, h3 = 0;
    if (valid) {
        float4 a = *reinterpret_cast<const float4*>(row);
        float4 b = *reinterpret_cast<const float4*>(row + 4);
        h0 = cvtpk(a.x, a.y); h1 = cvtpk(a.z, a.w);
        h2 = cvtpk(b.x, b.y); h3 = cvtpk(b.z, b.w);
    }
    return mk_frag(h0, h1, h2, h3);
}

__global__ __launch_bounds__(256) void fused_rnn_mlp_v10(
    const float* __restrict__ seqs,    // [N,1,B,2]
    const float* __restrict__ others,  // [1,B,14]
    const float* __restrict__ w_ih,    // [N,8,2]
    const float* __restrict__ b_ih,    // [N,8]
    const float* __restrict__ b_hh,    // [N,8]
    const float* __restrict__ w1,      // [24,24]
    const float* __restrict__ b1,      // [24]
    const float* __restrict__ w2,      // [5,24]
    const float* __restrict__ b2,      // [5]
    float* __restrict__ out)           // [B,5]
{
    const int tid  = threadIdx.x;
    const int lane = tid & 63;
    const int lo31 = lane & 31;        // elem-in-tile / weight row
    const int kh   = lane >> 5;        // 0: lanes 0-31, 1: lanes 32-63
    const int base = blockIdx.x * 512; // 2 groups x 256 elems

    // ---------- group-invariant: A-fragments + C1 bias init ----------
    const bf16x8 A1a = pack_row8(w1 + lo31 * 24 + 8 * kh, lo31 < 24);
    const bf16x8 A1b = pack_row8(w1 + lo31 * 24 + 16, (lo31 < 24) && (kh == 0));
    const bf16x8 A2a = pack_row8(w2 + lo31 * 24 + 8 * kh, lo31 < 5);
    const bf16x8 A2b = pack_row8(w2 + lo31 * 24 + 16, (lo31 < 5) && (kh == 0));

    f32x16 c1z;
#pragma unroll
    for (int r = 0; r < 16; r++) {
        const int jb = (r & 3) + 8 * (r >> 2);        // row for kh=0
        float v = 0.0f;
        if (jb < 24) v = kh ? b1[jb + 4] : b1[jb];
        c1z[r] = v;
    }

#pragma unroll
    for (int g = 0; g < 2; g++) {
        const int elem  = base + g * 256 + tid;
        const int wbase = base + g * 256 + (tid >> 6) * 64;

        // ---------- global loads ----------
        float2 x[Nc];
#pragma unroll
        for (int n = 0; n < Nc; n++)
            x[n] = *reinterpret_cast<const float2*>(
                seqs + ((size_t)n * Bc + elem) * 2);
        float2 oth[7];
        {
            const float2* op =
                reinterpret_cast<const float2*>(others + (size_t)elem * 14);
#pragma unroll
            for (int j = 0; j < 7; j++) oth[j] = op[j];
        }

        // ---------- LSTM (one step, h0=c0=0); pack feats into d[12] ----------
        unsigned d[12];
#pragma unroll
        for (int n = 0; n < Nc; n++) {
            const float* w = w_ih + n * 16;   // gate rows i(0,1) f(2,3) g(4,5) o(6,7)
            const float bi0 = b_ih[n*8+0] + b_hh[n*8+0];
            const float bi1 = b_ih[n*8+1] + b_hh[n*8+1];
            const float bg0 = b_ih[n*8+4] + b_hh[n*8+4];
            const float bg1 = b_ih[n*8+5] + b_hh[n*8+5];
            const float bo0 = b_ih[n*8+6] + b_hh[n*8+6];
            const float bo1 = b_ih[n*8+7] + b_hh[n*8+7];
            float gi0 = fmaf(x[n].x, w[0],  fmaf(x[n].y, w[1],  bi0));
            float gi1 = fmaf(x[n].x, w[2],  fmaf(x[n].y, w[3],  bi1));
            float gg0 = fmaf(x[n].x, w[8],  fmaf(x[n].y, w[9],  bg0));
            float gg1 = fmaf(x[n].x, w[10], fmaf(x[n].y, w[11], bg1));
            float go0 = fmaf(x[n].x, w[12], fmaf(x[n].y, w[13], bo0));
            float go1 = fmaf(x[n].x, w[14], fmaf(x[n].y, w[15], bo1));
            float c0 = sigtanh(gi0, gg0);
            float c1 = sigtanh(gi1, gg1);
            d[n] = cvtpk(sigtanh(go0, c0), sigtanh(go1, c1));
        }
#pragma unroll
        for (int j = 0; j < 7; j++)
            d[5 + j] = cvtpk(oth[j].x, oth[j].y);

        // ---------- cross-half copies of feats (lane <-> lane^32) ----------
        unsigned sd[12];
#pragma unroll
        for (int i = 0; i < 12; i++) sd[i] = __shfl_xor(d[i], 32);

        unsigned b0a[4], b1a[4], b0b[4], b1b[4];
#pragma unroll
        for (int i = 0; i < 4; i++) {
            b0a[i] = kh ? sd[4+i] : d[i];
            b1a[i] = kh ? d[4+i]  : sd[i];
            b0b[i] = kh ? 0u      : d[8+i];
            b1b[i] = kh ? 0u      : sd[8+i];
        }

        // ---------- FC1: 4 MFMAs (2 K-chunks x 2 tiles) ----------
        f32x16 accA = c1z, accB = c1z;
        accA = __builtin_amdgcn_mfma_f32_32x32x16_bf16(
            A1a, mk_frag(b0a[0], b0a[1], b0a[2], b0a[3]), accA, 0, 0, 0);
        accA = __builtin_amdgcn_mfma_f32_32x32x16_bf16(
            A1b, mk_frag(b0b[0], b0b[1], b0b[2], b0b[3]), accA, 0, 0, 0);
        accB = __builtin_amdgcn_mfma_f32_32x32x16_bf16(
            A1a, mk_frag(b1a[0], b1a[1], b1a[2], b1a[3]), accB, 0, 0, 0);
        accB = __builtin_amdgcn_mfma_f32_32x32x16_bf16(
            A1b, mk_frag(b1b[0], b1b[1], b1b[2], b1b[3]), accB, 0, 0, 0);

        // ---------- FC2 + sigmoid + store, per tile ----------
#pragma unroll
        for (int t = 0; t < 2; t++) {
            const f32x16 acc = t ? accB : accA;
            unsigned p0 = cvtpk(fmaxf(acc[0],  0.f), fmaxf(acc[1],  0.f));
            unsigned p1 = cvtpk(fmaxf(acc[2],  0.f), fmaxf(acc[3],  0.f));
            unsigned p2 = cvtpk(fmaxf(acc[4],  0.f), fmaxf(acc[5],  0.f));
            unsigned p3 = cvtpk(fmaxf(acc[6],  0.f), fmaxf(acc[7],  0.f));
            unsigned p4 = cvtpk(fmaxf(acc[8],  0.f), fmaxf(acc[9],  0.f));
            unsigned p5 = cvtpk(fmaxf(acc[10], 0.f), fmaxf(acc[11], 0.f));
            const unsigned q0 = __shfl_xor(p0, 32);
            const unsigned q1 = __shfl_xor(p1, 32);
            const unsigned q2 = __shfl_xor(p2, 32);
            const unsigned q3 = __shfl_xor(p3, 32);
            const unsigned q4 = __shfl_xor(p4, 32);
            const unsigned q5 = __shfl_xor(p5, 32);
            // B2 k0-15:  lo [p0 p1 q0 q1] (j0-7), hi [q2 q3 p2 p3] (j8-15)
            // B2 k16-31: lo [p4 p5 q4 q5] (j16-23), hi zero (pad)
            const bf16x8 B2a = mk_frag(kh ? q2 : p0, kh ? q3 : p1,
                                       kh ? p2 : q0, kh ? p3 : q1);
            const bf16x8 B2b = mk_frag(kh ? 0u : p4, kh ? 0u : p5,
                                       kh ? 0u : q4, kh ? 0u : q5);
            f32x16 c2;
#pragma unroll
            for (int r = 0; r < 16; r++) c2[r] = 0.0f;
            c2[0] = kh ? b2[4] : b2[0];
            if (!kh) { c2[1] = b2[1]; c2[2] = b2[2]; c2[3] = b2[3]; }
            c2 = __builtin_amdgcn_mfma_f32_32x32x16_bf16(A2a, B2a, c2, 0, 0, 0);
            c2 = __builtin_amdgcn_mfma_f32_32x32x16_bf16(A2b, B2b, c2, 0, 0, 0);

            const float s0 = fast_sigmoid(c2[0]);
            const float s1 = fast_sigmoid(c2[1]);
            const float s2 = fast_sigmoid(c2[2]);
            const float s3 = fast_sigmoid(c2[3]);
            const int et = wbase + t * 32 + lo31;
            float* o = out + (size_t)et * 5;
            if (kh == 0) {          // rows q=0..3
                o[0] = s0; o[1] = s1; o[2] = s2; o[3] = s3;
            } else {                // row q=4 (reg 0)
                o[4] = s0;
            }
        }
    }
}

extern "C" void kernel_launch(void* const* d_in, const int* in_sizes, int n_in,
                              void* d_out, int out_size, void* d_ws, size_t ws_size,
                              hipStream_t stream) {
    const float* seqs   = (const float*)d_in[0];
    const float* others = (const float*)d_in[1];
    const float* w_ih   = (const float*)d_in[2];
    // d_in[3] = w_hh : dead (h0 = 0)
    const float* b_ih   = (const float*)d_in[4];
    const float* b_hh   = (const float*)d_in[5];
    const float* w1     = (const float*)d_in[6];
    const float* b1     = (const float*)d_in[7];
    const float* w2     = (const float*)d_in[8];
    const float* b2     = (const float*)d_in[9];
    float* out = (float*)d_out;

    dim3 grid(Bc / 512), block(256);
    fused_rnn_mlp_v10<<<grid, block, 0, stream>>>(
        seqs, others, w_ih, b_ih, b_hh, w1, b1, w2, b2, out);
}

// Round 12
// 30.433 us; speedup vs baseline: 1.3236x; 1.0100x over previous
//
#include <hip/hip_runtime.h>

// B=1048576, N=5, H=2, CLS=24, OUT=5.  h0=c0=0 -> w_hh dead, f-gate dead.
// Round-11 resubmit (infra failure; kernel never ran). v10 structure
// (zero-LDS, 32x32x16 MFMA, 2 elem-groups/wave) with ALL __shfl_xor(.,32)
// replaced by v_permlane32_swap_b32 (CDNA4 VALU op, dual-output).
// r10 evidence: __shfl_xor compiles to ds_bpermute (DS pipe + lgkmcnt) and
// ~24 bpermutes + ~24 cndmasks per group sat on the critical path. Each
// permlane32_swap produces BOTH tile fragments at once, deleting all
// bpermutes AND all selects.

constexpr int Bc = 1048576;
constexpr int Nc = 5;

typedef __attribute__((ext_vector_type(8))) short bf16x8;
typedef __attribute__((ext_vector_type(16))) float f32x16;

__device__ __forceinline__ unsigned cvtpk(float lo, float hi) {
    unsigned r;
    asm("v_cvt_pk_bf16_f32 %0, %1, %2" : "=v"(r) : "v"(lo), "v"(hi));
    return r;
}
// v_permlane32_swap_b32 x, y:  x.lanes[32:63] <-> y.lanes[0:31]
// (LLVM gfx950: vsrc lanes 0-31 -> vdst lanes 32-63, vdst lanes 32-63 ->
// vsrc lanes 0-31). Both operands read-write.
__device__ __forceinline__ void swap32(unsigned &x, unsigned &y) {
    asm("v_permlane32_swap_b32 %0, %1" : "+v"(x), "+v"(y));
}
__device__ __forceinline__ float fast_sigmoid(float x) {
    return __builtin_amdgcn_rcpf(1.0f + __expf(-x));
}
// sigmoid(a)*tanh(b) with a single rcp
__device__ __forceinline__ float sigtanh(float a, float b) {
    float ea = __expf(-a);
    float eb = __expf(2.0f * b);
    return (eb - 1.0f) * __builtin_amdgcn_rcpf((eb + 1.0f) * (1.0f + ea));
}
__device__ __forceinline__ bf16x8 mk_frag(unsigned a, unsigned b,
                                          unsigned c, unsigned d) {
    union { uint4 u; bf16x8 v; } x;
    x.u = make_uint4(a, b, c, d);
    return x.v;
}
// 8 consecutive floats of one weight row -> bf16 fragment (zeros if !valid)
__device__ __forceinline__ bf16x8 pack_row8(const float* row, bool valid) {
    unsigned h0 = 0, h1 = 0, h2 = 0, h3 = 0;
    if (valid) {
        float4 a = *reinterpret_cast<const float4*>(row);
        float4 b = *reinterpret_cast<const float4*>(row + 4);
        h0 = cvtpk(a.x, a.y); h1 = cvtpk(a.z, a.w);
        h2 = cvtpk(b.x, b.y); h3 = cvtpk(b.z, b.w);
    }
    return mk_frag(h0, h1, h2, h3);
}

__global__ __launch_bounds__(256) void fused_rnn_mlp_v11(
    const float* __restrict__ seqs,    // [N,1,B,2]
    const float* __restrict__ others,  // [1,B,14]
    const float* __restrict__ w_ih,    // [N,8,2]
    const float* __restrict__ b_ih,    // [N,8]
    const float* __restrict__ b_hh,    // [N,8]
    const float* __restrict__ w1,      // [24,24]
    const float* __restrict__ b1,      // [24]
    const float* __restrict__ w2,      // [5,24]
    const float* __restrict__ b2,      // [5]
    float* __restrict__ out)           // [B,5]
{
    const int tid  = threadIdx.x;
    const int lane = tid & 63;
    const int lo31 = lane & 31;        // elem-in-tile / weight row
    const int kh   = lane >> 5;        // 0: lanes 0-31, 1: lanes 32-63
    const int base = blockIdx.x * 512; // 2 groups x 256 elems

    // ---------- group-invariant: A-fragments + C1 bias init ----------
    const bf16x8 A1a = pack_row8(w1 + lo31 * 24 + 8 * kh, lo31 < 24);
    const bf16x8 A1b = pack_row8(w1 + lo31 * 24 + 16, (lo31 < 24) && (kh == 0));
    const bf16x8 A2a = pack_row8(w2 + lo31 * 24 + 8 * kh, lo31 < 5);
    const bf16x8 A2b = pack_row8(w2 + lo31 * 24 + 16, (lo31 < 5) && (kh == 0));

    f32x16 c1z;
#pragma unroll
    for (int r = 0; r < 16; r++) {
        const int jb = (r & 3) + 8 * (r >> 2);        // row for kh=0
        float v = 0.0f;
        if (jb < 24) v = kh ? b1[jb + 4] : b1[jb];
        c1z[r] = v;
    }

#pragma unroll
    for (int g = 0; g < 2; g++) {
        const int elem  = base + g * 256 + tid;
        const int wbase = base + g * 256 + (tid >> 6) * 64;

        // ---------- global loads ----------
        float2 x[Nc];
#pragma unroll
        for (int n = 0; n < Nc; n++)
            x[n] = *reinterpret_cast<const float2*>(
                seqs + ((size_t)n * Bc + elem) * 2);
        float2 oth[7];
        {
            const float2* op =
                reinterpret_cast<const float2*>(others + (size_t)elem * 14);
#pragma unroll
            for (int j = 0; j < 7; j++) oth[j] = op[j];
        }

        // ---------- LSTM (one step, h0=c0=0); pack feats into d[12] ----------
        unsigned d[12];
#pragma unroll
        for (int n = 0; n < Nc; n++) {
            const float* w = w_ih + n * 16;   // gate rows i(0,1) f(2,3) g(4,5) o(6,7)
            const float bi0 = b_ih[n*8+0] + b_hh[n*8+0];
            const float bi1 = b_ih[n*8+1] + b_hh[n*8+1];
            const float bg0 = b_ih[n*8+4] + b_hh[n*8+4];
            const float bg1 = b_ih[n*8+5] + b_hh[n*8+5];
            const float bo0 = b_ih[n*8+6] + b_hh[n*8+6];
            const float bo1 = b_ih[n*8+7] + b_hh[n*8+7];
            float gi0 = fmaf(x[n].x, w[0],  fmaf(x[n].y, w[1],  bi0));
            float gi1 = fmaf(x[n].x, w[2],  fmaf(x[n].y, w[3],  bi1));
            float gg0 = fmaf(x[n].x, w[8],  fmaf(x[n].y, w[9],  bg0));
            float gg1 = fmaf(x[n].x, w[10], fmaf(x[n].y, w[11], bg1));
            float go0 = fmaf(x[n].x, w[12], fmaf(x[n].y, w[13], bo0));
            float go1 = fmaf(x[n].x, w[14], fmaf(x[n].y, w[15], bo1));
            float c0 = sigtanh(gi0, gg0);
            float c1 = sigtanh(gi1, gg1);
            d[n] = cvtpk(sigtanh(go0, c0), sigtanh(go1, c1));
        }
#pragma unroll
        for (int j = 0; j < 7; j++)
            d[5 + j] = cvtpk(oth[j].x, oth[j].y);

        // ---------- FC1 B-fragments via permlane32_swap (dual-output) ----------
        // b0a = {d[i] own | d[4+i] from l-32}   (tile0, k0-15)
        // b1a = {d[i] from l+32 | d[4+i] own}   (tile1, k0-15)
        // b0b = {d[8+i] own | 0}                (tile0, k16-31)
        // b1b = {d[8+i] from l+32 | 0}          (tile1, k16-31)
        unsigned b0a[4], b1a[4], b0b[4], b1b[4];
#pragma unroll
        for (int i = 0; i < 4; i++) {
            b0a[i] = d[i];     b1a[i] = d[4 + i];  swap32(b0a[i], b1a[i]);
            b0b[i] = d[8 + i]; b1b[i] = 0u;        swap32(b0b[i], b1b[i]);
        }

        // ---------- FC1: 4 MFMAs (2 K-chunks x 2 tiles) ----------
        f32x16 accA = c1z, accB = c1z;
        accA = __builtin_amdgcn_mfma_f32_32x32x16_bf16(
            A1a, mk_frag(b0a[0], b0a[1], b0a[2], b0a[3]), accA, 0, 0, 0);
        accA = __builtin_amdgcn_mfma_f32_32x32x16_bf16(
            A1b, mk_frag(b0b[0], b0b[1], b0b[2], b0b[3]), accA, 0, 0, 0);
        accB = __builtin_amdgcn_mfma_f32_32x32x16_bf16(
            A1a, mk_frag(b1a[0], b1a[1], b1a[2], b1a[3]), accB, 0, 0, 0);
        accB = __builtin_amdgcn_mfma_f32_32x32x16_bf16(
            A1b, mk_frag(b1b[0], b1b[1], b1b[2], b1b[3]), accB, 0, 0, 0);

        // ---------- FC2 + sigmoid + store, per tile ----------
#pragma unroll
        for (int t = 0; t < 2; t++) {
            const f32x16 acc = t ? accB : accA;
            unsigned p0 = cvtpk(fmaxf(acc[0],  0.f), fmaxf(acc[1],  0.f));
            unsigned p1 = cvtpk(fmaxf(acc[2],  0.f), fmaxf(acc[3],  0.f));
            unsigned p2 = cvtpk(fmaxf(acc[4],  0.f), fmaxf(acc[5],  0.f));
            unsigned p3 = cvtpk(fmaxf(acc[6],  0.f), fmaxf(acc[7],  0.f));
            unsigned p4 = cvtpk(fmaxf(acc[8],  0.f), fmaxf(acc[9],  0.f));
            unsigned p5 = cvtpk(fmaxf(acc[10], 0.f), fmaxf(acc[11], 0.f));
            // B2a words: {p0|q2, p1|q3, q0|p2, q1|p3} via 2 swaps
            unsigned w0 = p0, w2 = p2;  swap32(w0, w2);
            unsigned w1 = p1, w3 = p3;  swap32(w1, w3);
            // B2b words: {p4|0, p5|0, q4|0, q5|0} via 2 swaps with zero
            unsigned u0 = p4, u2 = 0u;  swap32(u0, u2);
            unsigned u1 = p5, u3 = 0u;  swap32(u1, u3);
            const bf16x8 B2a = mk_frag(w0, w1, w2, w3);
            const bf16x8 B2b = mk_frag(u0, u1, u2, u3);

            f32x16 c2;
#pragma unroll
            for (int r = 0; r < 16; r++) c2[r] = 0.0f;
            c2[0] = kh ? b2[4] : b2[0];
            if (!kh) { c2[1] = b2[1]; c2[2] = b2[2]; c2[3] = b2[3]; }
            c2 = __builtin_amdgcn_mfma_f32_32x32x16_bf16(A2a, B2a, c2, 0, 0, 0);
            c2 = __builtin_amdgcn_mfma_f32_32x32x16_bf16(A2b, B2b, c2, 0, 0, 0);

            const float s0 = fast_sigmoid(c2[0]);
            const float s1 = fast_sigmoid(c2[1]);
            const float s2 = fast_sigmoid(c2[2]);
            const float s3 = fast_sigmoid(c2[3]);
            const int et = wbase + t * 32 + lo31;
            float* o = out + (size_t)et * 5;
            if (kh == 0) {          // rows q=0..3
                o[0] = s0; o[1] = s1; o[2] = s2; o[3] = s3;
            } else {                // row q=4 (reg 0)
                o[4] = s0;
            }
        }
    }
}

extern "C" void kernel_launch(void* const* d_in, const int* in_sizes, int n_in,
                              void* d_out, int out_size, void* d_ws, size_t ws_size,
                              hipStream_t stream) {
    const float* seqs   = (const float*)d_in[0];
    const float* others = (const float*)d_in[1];
    const float* w_ih   = (const float*)d_in[2];
    // d_in[3] = w_hh : dead (h0 = 0)
    const float* b_ih   = (const float*)d_in[4];
    const float* b_hh   = (const float*)d_in[5];
    const float* w1     = (const float*)d_in[6];
    const float* b1     = (const float*)d_in[7];
    const float* w2     = (const float*)d_in[8];
    const float* b2     = (const float*)d_in[9];
    float* out = (float*)d_out;

    dim3 grid(Bc / 512), block(256);
    fused_rnn_mlp_v11<<<grid, block, 0, stream>>>(
        seqs, others, w_ih, b_ih, b_hh, w1, b1, w2, b2, out);
}